// Round 2
// baseline (509.939 us; speedup 1.0000x reference)
//
#include <hip/hip_runtime.h>
#include <hip/hip_bf16.h>
#include <stdint.h>

typedef __hip_bfloat16 bf16;
typedef __attribute__((ext_vector_type(4))) float f32x4;
typedef __attribute__((ext_vector_type(8))) short short8;

#define DEVI static __device__ __forceinline__

// async global->LDS, 16B per lane. LDS dest must be wave-uniform base; HW adds lane*16.
DEVI void gload_lds16(const bf16* g, bf16* l) {
  __builtin_amdgcn_global_load_lds(
      (const __attribute__((address_space(1))) unsigned int*)g,
      (__attribute__((address_space(3))) unsigned int*)l, 16, 0, 0);
}

// ---------------- fp32 -> bf16 elementwise convert (8 elems/thread) ----------------
__global__ __launch_bounds__(256) void cvt_f32_bf16(const float* __restrict__ in,
                                                    bf16* __restrict__ out, int n8) {
  int i = blockIdx.x * blockDim.x + threadIdx.x;
  if (i >= n8) return;
  const float4 a = *(const float4*)(in + (size_t)i * 8);
  const float4 b = *(const float4*)(in + (size_t)i * 8 + 4);
  bf16 t[8];
  t[0] = __float2bfloat16(a.x); t[1] = __float2bfloat16(a.y);
  t[2] = __float2bfloat16(a.z); t[3] = __float2bfloat16(a.w);
  t[4] = __float2bfloat16(b.x); t[5] = __float2bfloat16(b.y);
  t[6] = __float2bfloat16(b.z); t[7] = __float2bfloat16(b.w);
  *(short8*)(out + (size_t)i * 8) = *(const short8*)t;
}

// ---------- fp32 [R][C] -> bf16 [C][R] tiled transpose+convert (64x64 tiles) ----------
__global__ __launch_bounds__(256) void transpose_cvt(const float* __restrict__ in,
                                                     bf16* __restrict__ out,
                                                     int R, int C) {
  __shared__ bf16 tile[64][72];  // [c][r], +8 pad breaks bank alignment
  const int c0 = blockIdx.x * 64, r0 = blockIdx.y * 64;
  const int t = threadIdx.x;
#pragma unroll
  for (int i = 0; i < 4; i++) {
    int idx = (i * 256 + t) * 4;
    int r = idx >> 6, c = idx & 63;
    float4 v = *(const float4*)&in[(size_t)(r0 + r) * C + c0 + c];
    tile[c + 0][r] = __float2bfloat16(v.x);
    tile[c + 1][r] = __float2bfloat16(v.y);
    tile[c + 2][r] = __float2bfloat16(v.z);
    tile[c + 3][r] = __float2bfloat16(v.w);
  }
  __syncthreads();
#pragma unroll
  for (int i = 0; i < 2; i++) {
    int idx = (i * 256 + t) * 8;
    int c = idx >> 6, r = idx & 63;
    *(short8*)&out[(size_t)(c0 + c) * R + r0 + r] = *(const short8*)&tile[c][r];
  }
}

// ------- extract V head-blocks from qkv and transpose: vt[bh][d=128][s=2048] -------
__global__ __launch_bounds__(256) void build_vt(const bf16* __restrict__ qkv,
                                                bf16* __restrict__ vt) {
  __shared__ bf16 tile[64][72];  // [d][s]
  const int bh = blockIdx.z, b = bh >> 4, h = bh & 15;
  const bf16* src = qkv + (size_t)b * 2048 * 6144 + 4096 + (size_t)h * 128;
  bf16* dst = vt + (size_t)bh * 128 * 2048;
  const int s0 = blockIdx.y * 64, d0 = blockIdx.x * 64;
  const int t = threadIdx.x;
#pragma unroll
  for (int i = 0; i < 2; i++) {
    int idx = (i * 256 + t) * 8;
    int r = idx >> 6, c = idx & 63;  // r = s-local, c = d-local (8-chunk)
    short8 v = *(const short8*)&src[(size_t)(s0 + r) * 6144 + d0 + c];
    bf16* vv = (bf16*)&v;
#pragma unroll
    for (int j = 0; j < 8; j++) tile[c + j][r] = vv[j];
  }
  __syncthreads();
#pragma unroll
  for (int i = 0; i < 2; i++) {
    int idx = (i * 256 + t) * 8;
    int r = idx >> 6, c = idx & 63;  // r = d-local, c = s-local
    *(short8*)&dst[(size_t)(d0 + r) * 2048 + s0 + c] = *(const short8*)&tile[r][c];
  }
}

// ---------------- m97-structure GEMM: C[M][N] = A[M][K] * Bt[N][K]^T + bias ----------------
// A,Bt bf16 row-major. 128x128 tile, BK=32, 256 threads (2x2 waves, 64x64 each).
template <int OUT_BF16>
__global__ __launch_bounds__(256, 2) void gemm_bt(const bf16* __restrict__ A,
                                                  const bf16* __restrict__ Bt,
                                                  const float* __restrict__ bias,
                                                  void* __restrict__ C,
                                                  const int M, const int N, const int K) {
  __shared__ bf16 As[128 * 32];
  __shared__ bf16 Bs[128 * 32];
  const int t = threadIdx.x, lane = t & 63, w = t >> 6;
  const int wr = w >> 1, wc = w & 1;
  const int lrow = lane >> 4, lcol = lane & 15;

  // bijective XCD swizzle (grids are multiples of 8 blocks)
  int bid = blockIdx.y * gridDim.x + blockIdx.x;
  const int nwg = gridDim.x * gridDim.y;
  bid = (bid & 7) * (nwg >> 3) + (bid >> 3);
  const int bx = bid % gridDim.x, by = bid / gridDim.x;
  const int m0 = by * 128, n0 = bx * 128;

  f32x4 acc[4][4];
#pragma unroll
  for (int i = 0; i < 4; i++)
#pragma unroll
    for (int j = 0; j < 4; j++) acc[i][j] = (f32x4){0.f, 0.f, 0.f, 0.f};

  for (int k0 = 0; k0 < K; k0 += 32) {
    __syncthreads();
#pragma unroll
    for (int i = 0; i < 2; i++) {
      const int o = i * 256 + t;
      gload_lds16(&A[(size_t)(m0 + (o >> 2)) * K + k0 + ((o & 3) << 3)],
                  &As[(i * 256 + w * 64) * 8]);
      gload_lds16(&Bt[(size_t)(n0 + (o >> 2)) * K + k0 + ((o & 3) << 3)],
                  &Bs[(i * 256 + w * 64) * 8]);
    }
    asm volatile("s_waitcnt vmcnt(0)" ::: "memory");
    __syncthreads();
    short8 af[4], bfr[4];
#pragma unroll
    for (int m = 0; m < 4; m++)
      af[m] = *(const short8*)&As[(wr * 64 + m * 16 + lcol) * 32 + lrow * 8];
#pragma unroll
    for (int n = 0; n < 4; n++)
      bfr[n] = *(const short8*)&Bs[(wc * 64 + n * 16 + lcol) * 32 + lrow * 8];
#pragma unroll
    for (int m = 0; m < 4; m++)
#pragma unroll
      for (int n = 0; n < 4; n++)
        acc[m][n] = __builtin_amdgcn_mfma_f32_16x16x32_bf16(af[m], bfr[n], acc[m][n], 0, 0, 0);
  }

  // epilogue: C row = m0+wr*64+m*16+lrow*4+r, col = n0+wc*64+n*16+lcol
  float bs[4];
#pragma unroll
  for (int n = 0; n < 4; n++) bs[n] = bias[n0 + wc * 64 + n * 16 + lcol];
#pragma unroll
  for (int m = 0; m < 4; m++) {
#pragma unroll
    for (int n = 0; n < 4; n++) {
      const int row = m0 + wr * 64 + m * 16 + lrow * 4;
      const int col = n0 + wc * 64 + n * 16 + lcol;
#pragma unroll
      for (int r = 0; r < 4; r++) {
        float v = acc[m][n][r] + bs[n];
        if (OUT_BF16)
          ((bf16*)C)[(size_t)(row + r) * N + col] = __float2bfloat16(v);
        else
          ((float*)C)[(size_t)(row + r) * N + col] = v;
      }
    }
  }
}

// ---------------- flash causal attention ----------------
// Q-tile 128 rows/block, 4 waves x 32 rows. K-tile 64. LDS-staged K and V^T (padded).
// P goes through per-wave LDS to convert C-layout -> A-layout for the PV MFMA.
#define SM_SCALE 0.08838834764831845f

__global__ __launch_bounds__(256, 2) void flash_attn(const bf16* __restrict__ qkv,
                                                     const bf16* __restrict__ vt,
                                                     bf16* __restrict__ attn) {
  constexpr int S = 2048, TH = 6144, HH = 2048, D = 128;
  __shared__ bf16 Kl[64][136];     // [k][d], stride 272B -> 2-way bank (free)
  __shared__ bf16 Vl[128][72];     // [d][k], stride 144B -> 2-way bank
  __shared__ bf16 Pl[4][32][72];   // per-wave P buffer
  const int t = threadIdx.x, lane = t & 63, w = t >> 6;
  const int lrow = lane >> 4, lcol = lane & 15;
  const int bh = blockIdx.y, b = bh >> 4, h = bh & 15;
  const int q0 = blockIdx.x * 128;
  const bf16* Qp = qkv + (size_t)b * S * TH + (size_t)h * D;
  const bf16* Kp = qkv + (size_t)b * S * TH + 2048 + (size_t)h * D;
  const bf16* Vp = vt + (size_t)bh * D * S;

  // Q fragments held in registers for the whole block
  short8 aq[2][4];
#pragma unroll
  for (int m = 0; m < 2; m++)
#pragma unroll
    for (int kc = 0; kc < 4; kc++)
      aq[m][kc] = *(const short8*)&Qp[(size_t)(q0 + w * 32 + m * 16 + lcol) * TH +
                                      kc * 32 + lrow * 8];

  f32x4 o[2][8];
#pragma unroll
  for (int m = 0; m < 2; m++)
#pragma unroll
    for (int nd = 0; nd < 8; nd++) o[m][nd] = (f32x4){0.f, 0.f, 0.f, 0.f};
  float mx[2][4], ls[2][4];
#pragma unroll
  for (int m = 0; m < 2; m++)
#pragma unroll
    for (int r = 0; r < 4; r++) { mx[m][r] = -1e30f; ls[m][r] = 0.f; }

  const int ktend = q0 / 64 + 2;  // covers k0 <= q0+127
  for (int kt = 0; kt < ktend; ++kt) {
    const int k0 = kt * 64;
    __syncthreads();  // previous tile fully consumed
#pragma unroll
    for (int i = 0; i < 4; i++) {  // stage K: 64 x 128 = 8192 elems (4*256*8)
      int idx = (i * 256 + t) * 8;
      int r = idx >> 7, c = idx & 127;
      *(short8*)&Kl[r][c] = *(const short8*)&Kp[(size_t)(k0 + r) * TH + c];
    }
#pragma unroll
    for (int i = 0; i < 4; i++) {  // stage V^T: 128 x 64 = 8192 elems
      int idx = (i * 256 + t) * 8;
      int r = idx >> 6, c = idx & 63;
      *(short8*)&Vl[r][c] = *(const short8*)&Vp[(size_t)r * S + k0 + c];
    }
    __syncthreads();

    if (k0 > q0 + w * 32 + 31) continue;  // tile fully masked for this wave (barriers stay matched)

    // S = Q K^T (C-layout: row=q=(lrow*4+reg), col=k=lcol)
    f32x4 s[2][4];
#pragma unroll
    for (int m = 0; m < 2; m++)
#pragma unroll
      for (int n = 0; n < 4; n++) s[m][n] = (f32x4){0.f, 0.f, 0.f, 0.f};
#pragma unroll
    for (int n = 0; n < 4; n++) {
      short8 bk[4];
#pragma unroll
      for (int kc = 0; kc < 4; kc++)
        bk[kc] = *(const short8*)&Kl[n * 16 + lcol][kc * 32 + lrow * 8];
#pragma unroll
      for (int m = 0; m < 2; m++)
#pragma unroll
        for (int kc = 0; kc < 4; kc++)
          s[m][n] = __builtin_amdgcn_mfma_f32_16x16x32_bf16(aq[m][kc], bk[kc], s[m][n], 0, 0, 0);
    }

    const bool needmask = (k0 + 63) > (q0 + w * 32);
#pragma unroll
    for (int m = 0; m < 2; m++)
#pragma unroll
      for (int n = 0; n < 4; n++)
#pragma unroll
        for (int r = 0; r < 4; r++) {
          float v = s[m][n][r] * SM_SCALE;
          if (needmask) {
            int qg = q0 + w * 32 + m * 16 + lrow * 4 + r;
            int kg = k0 + n * 16 + lcol;
            if (kg > qg) v = -1e30f;
          }
          s[m][n][r] = v;
        }

    // online softmax per q-row (row lives on 16 lanes: shfl_xor 1,2,4,8)
#pragma unroll
    for (int m = 0; m < 2; m++)
#pragma unroll
      for (int r = 0; r < 4; r++) {
        float rm = fmaxf(fmaxf(s[m][0][r], s[m][1][r]), fmaxf(s[m][2][r], s[m][3][r]));
        rm = fmaxf(rm, __shfl_xor(rm, 1));
        rm = fmaxf(rm, __shfl_xor(rm, 2));
        rm = fmaxf(rm, __shfl_xor(rm, 4));
        rm = fmaxf(rm, __shfl_xor(rm, 8));
        const float mn = fmaxf(mx[m][r], rm);
        const float fac = __expf(mx[m][r] - mn);
        mx[m][r] = mn;
        float rs = 0.f;
#pragma unroll
        for (int n = 0; n < 4; n++) {
          float p = __expf(s[m][n][r] - mn);
          s[m][n][r] = p;
          rs += p;
        }
        rs += __shfl_xor(rs, 1);
        rs += __shfl_xor(rs, 2);
        rs += __shfl_xor(rs, 4);
        rs += __shfl_xor(rs, 8);
        ls[m][r] = ls[m][r] * fac + rs;
        // rescale ONLY component r (row = lrow*4 + r) of each f32x4
#pragma unroll
        for (int nd = 0; nd < 8; nd++) o[m][nd][r] *= fac;
      }

    // P -> per-wave LDS (C-layout scatter), reload as A-fragments
#pragma unroll
    for (int m = 0; m < 2; m++)
#pragma unroll
      for (int n = 0; n < 4; n++)
#pragma unroll
        for (int r = 0; r < 4; r++)
          Pl[w][m * 16 + lrow * 4 + r][n * 16 + lcol] = __float2bfloat16(s[m][n][r]);

    short8 ap[2][2];
#pragma unroll
    for (int m = 0; m < 2; m++)
#pragma unroll
      for (int kc = 0; kc < 2; kc++)
        ap[m][kc] = *(const short8*)&Pl[w][m * 16 + lcol][kc * 32 + lrow * 8];

    // O += P V
#pragma unroll
    for (int nd = 0; nd < 8; nd++) {
      short8 bv[2];
#pragma unroll
      for (int kc = 0; kc < 2; kc++)
        bv[kc] = *(const short8*)&Vl[nd * 16 + lcol][kc * 32 + lrow * 8];
#pragma unroll
      for (int m = 0; m < 2; m++)
#pragma unroll
        for (int kc = 0; kc < 2; kc++)
          o[m][nd] = __builtin_amdgcn_mfma_f32_16x16x32_bf16(ap[m][kc], bv[kc], o[m][nd], 0, 0, 0);
    }
  }

  // epilogue: attn[b, q, h*128 + d] bf16
#pragma unroll
  for (int m = 0; m < 2; m++)
#pragma unroll
    for (int nd = 0; nd < 8; nd++)
#pragma unroll
      for (int r = 0; r < 4; r++)
        attn[(size_t)(b * S + q0 + w * 32 + m * 16 + lrow * 4 + r) * HH + h * D +
             nd * 16 + lcol] = __float2bfloat16(o[m][nd][r] / ls[m][r]);
}

extern "C" void kernel_launch(void* const* d_in, const int* in_sizes, int n_in,
                              void* d_out, int out_size, void* d_ws, size_t ws_size,
                              hipStream_t stream) {
  const float* hidden = (const float*)d_in[0];  // [2,2048,2048]
  const float* w_attn = (const float*)d_in[1];  // [2048,6144]
  const float* b_attn = (const float*)d_in[2];  // [6144]
  const float* w_proj = (const float*)d_in[3];  // [2048,2048]
  const float* b_proj = (const float*)d_in[4];  // [2048]

  char* ws = (char*)d_ws;
  bf16* hb    = (bf16*)(ws);                 // [4096][2048]        16 MB
  bf16* wab_t = (bf16*)(ws + 16777216ull);   // [6144][2048]        24 MB
  bf16* wpb_t = (bf16*)(ws + 41943040ull);   // [2048][2048]         8 MB
  bf16* qkv   = (bf16*)(ws + 50331648ull);   // [4096][6144]        48 MB
  bf16* vt    = (bf16*)(ws + 100663296ull);  // [32][128][2048]     16 MB
  bf16* attn  = (bf16*)(ws + 117440512ull);  // [4096][2048]        16 MB  (total 128 MB)

  cvt_f32_bf16<<<4096, 256, 0, stream>>>(hidden, hb, 4096 * 2048 / 8);
  transpose_cvt<<<dim3(96, 32), 256, 0, stream>>>(w_attn, wab_t, 2048, 6144);
  transpose_cvt<<<dim3(32, 32), 256, 0, stream>>>(w_proj, wpb_t, 2048, 2048);
  gemm_bt<1><<<dim3(48, 32), 256, 0, stream>>>(hb, wab_t, b_attn, (void*)qkv, 4096, 6144, 2048);
  build_vt<<<dim3(2, 32, 32), 256, 0, stream>>>(qkv, vt);
  flash_attn<<<dim3(16, 32), 256, 0, stream>>>(qkv, vt, attn);
  gemm_bt<0><<<dim3(16, 32), 256, 0, stream>>>(attn, wpb_t, b_proj, d_out, 4096, 2048, 2048);
}